// Round 2
// baseline (242778.394 us; speedup 1.0000x reference)
//
#include <hip/hip_runtime.h>
#include <stdint.h>

typedef unsigned long long u64;

#define T_TOTAL 65536
#define ISZ 256
#define HSZ 512
#define NBLK 32
#define SLICE 16   // HSZ / NBLK

// ---------------------------------------------------------------------------
// Persistent fused GRU scan. 32 blocks x 256 threads, 1 block/CU.
// Block g owns hidden units [16g,16g+16): rows {j*512 + 16g + loc} of w_hh
// and w_ih for gates j=0(reset),1(update),2(new). All weights in VGPRs.
//
// Thread layout: seg = tid&15 (K-segment: h[32*seg..+32), x[16*seg..+16)),
//                rg  = tid>>4 (unit within slice, 0..15).
// Per thread: whh[3][32] (96 regs), wih[3][16] (48 regs).
//
// h exchange: tagged 64-bit slots {tag=version, f32 value} in d_ws,
// release/acquire at agent scope. Version v lives in hslot[v&1][*]; tag 0 ==
// h_0 == 0 matches the memset. 2-deep parity ring is overwrite-safe: a block
// publishes version s+1 only after reading ALL of version s, which
// happens-after every block published s, which happens-after their reads of
// s-1 completed.
//
// Spin fuse: total poll budget per thread; if the protocol ever stalls
// (non-residency etc.) the kernel terminates with wrong values instead of
// wedging the container.
// ---------------------------------------------------------------------------
__global__ __launch_bounds__(256, 1) void gru_fused(
    const float* __restrict__ xs, const float* __restrict__ w_ih,
    const float* __restrict__ w_hh, const float* __restrict__ bias,
    const float* __restrict__ bias_n, u64* __restrict__ hslot,
    float* __restrict__ out) {
  const int g   = blockIdx.x;
  const int tid = threadIdx.x;
  const int seg = tid & 15;
  const int rg  = tid >> 4;

  __shared__ float x_lds[ISZ];
  __shared__ float h_lds[HSZ];
  __shared__ float hg_lds[64];

  // Load weight fragments (rows j*512 + g*16 + rg, gate j = 0..2).
  float whh[3][32];
  float wih[3][16];
#pragma unroll
  for (int j = 0; j < 3; ++j) {
    const float* srcH = w_hh + (size_t)(j * HSZ + g * SLICE + rg) * HSZ + seg * 32;
#pragma unroll
    for (int u = 0; u < 8; ++u) {
      float4 v = *(const float4*)(srcH + u * 4);
      whh[j][u * 4 + 0] = v.x; whh[j][u * 4 + 1] = v.y;
      whh[j][u * 4 + 2] = v.z; whh[j][u * 4 + 3] = v.w;
    }
    const float* srcI = w_ih + (size_t)(j * HSZ + g * SLICE + rg) * ISZ + seg * 16;
#pragma unroll
    for (int u = 0; u < 4; ++u) {
      float4 v = *(const float4*)(srcI + u * 4);
      wih[j][u * 4 + 0] = v.x; wih[j][u * 4 + 1] = v.y;
      wih[j][u * 4 + 2] = v.z; wih[j][u * 4 + 3] = v.w;
    }
  }

  float br = 0.f, bz = 0.f, bnn = 0.f, bn2 = 0.f;
  if (tid < SLICE) {
    br  = bias[g * SLICE + tid];
    bz  = bias[HSZ + g * SLICE + tid];
    bnn = bias[2 * HSZ + g * SLICE + tid];
    bn2 = bias_n[g * SLICE + tid];
  }

  long long budget = 50000000;  // total spin-poll fuse per thread

  for (int s = 0; s < T_TOTAL; ++s) {
    // Stage x[s] (off the h-dependency chain).
    if (tid < 64) {
      float4 v = *(const float4*)(xs + (size_t)s * ISZ + tid * 4);
      *(float4*)&x_lds[tid * 4] = v;
    }
    __syncthreads();  // B1: x ready; also fences prev-iter h_lds/hg_lds reads

    // Input-side gate dots (independent of h): a0=reset, a1=update, a2=ig_n.
    float a0 = 0.f, a1 = 0.f, a2 = 0.f, a3 = 0.f;  // a3 = hg_n (h part, kept separate)
#pragma unroll
    for (int u = 0; u < 4; ++u) {
      float4 xv = *(const float4*)&x_lds[seg * 16 + u * 4];
      a0 += wih[0][u*4+0]*xv.x + wih[0][u*4+1]*xv.y + wih[0][u*4+2]*xv.z + wih[0][u*4+3]*xv.w;
      a1 += wih[1][u*4+0]*xv.x + wih[1][u*4+1]*xv.y + wih[1][u*4+2]*xv.z + wih[1][u*4+3]*xv.w;
      a2 += wih[2][u*4+0]*xv.x + wih[2][u*4+1]*xv.y + wih[2][u*4+2]*xv.z + wih[2][u*4+3]*xv.w;
    }

    // Acquire h version s (each thread owns 2 of the 512 slots).
    u64* slots = hslot + (size_t)(s & 1) * HSZ;
    u64 v0, v1;
    do {
      v0 = __hip_atomic_load(&slots[tid], __ATOMIC_ACQUIRE, __HIP_MEMORY_SCOPE_AGENT);
    } while ((unsigned)(v0 >> 32) != (unsigned)s && --budget > 0);
    do {
      v1 = __hip_atomic_load(&slots[tid + 256], __ATOMIC_ACQUIRE, __HIP_MEMORY_SCOPE_AGENT);
    } while ((unsigned)(v1 >> 32) != (unsigned)s && --budget > 0);
    h_lds[tid]       = __uint_as_float((unsigned)v0);
    h_lds[tid + 256] = __uint_as_float((unsigned)v1);
    __syncthreads();  // B2: h ready

    // Hidden-side dots (on the critical chain): 3 rows x 32-wide segment.
#pragma unroll
    for (int u = 0; u < 8; ++u) {
      float4 hv = *(const float4*)&h_lds[seg * 32 + u * 4];
      a0 += whh[0][u*4+0]*hv.x + whh[0][u*4+1]*hv.y + whh[0][u*4+2]*hv.z + whh[0][u*4+3]*hv.w;
      a1 += whh[1][u*4+0]*hv.x + whh[1][u*4+1]*hv.y + whh[1][u*4+2]*hv.z + whh[1][u*4+3]*hv.w;
      a3 += whh[2][u*4+0]*hv.x + whh[2][u*4+1]*hv.y + whh[2][u*4+2]*hv.z + whh[2][u*4+3]*hv.w;
    }

    // Reduce across the 16 seg-lanes (tid bits 0..3).
#pragma unroll
    for (int p = 0; p < 4; ++p) {
      int m = 1 << p;
      a0 += __shfl_xor(a0, m, 64);
      a1 += __shfl_xor(a1, m, 64);
      a2 += __shfl_xor(a2, m, 64);
      a3 += __shfl_xor(a3, m, 64);
    }
    if (seg == 0) hg_lds[rg]      = a0;
    if (seg == 1) hg_lds[16 + rg] = a1;
    if (seg == 2) hg_lds[32 + rg] = a2;
    if (seg == 3) hg_lds[48 + rg] = a3;
    __syncthreads();  // B3: gate pre-activations ready

    if (tid < SLICE) {
      float pr  = br  + hg_lds[tid];        // reset pre-act (ig+hg merged)
      float pz  = bz  + hg_lds[16 + tid];   // update pre-act
      float ign = bnn + hg_lds[32 + tid];   // input-side n + bias
      float hgn = hg_lds[48 + tid];         // hidden-side n
      float r  = 1.f / (1.f + expf(-pr));
      float z  = 1.f / (1.f + expf(-pz));
      float nn = tanhf(ign + r * (hgn + bn2));
      const int hid = g * SLICE + tid;
      float hold = h_lds[hid];
      float hnew = nn + z * (hold - nn);
      out[(size_t)HSZ + (size_t)s * HSZ + hid] = hnew;
      if (s == T_TOTAL - 1) out[hid] = hnew;
      u64 pw = ((u64)(unsigned)(s + 1) << 32) | (u64)__float_as_uint(hnew);
      __hip_atomic_store(&hslot[(size_t)((s + 1) & 1) * HSZ + hid], pw,
                         __ATOMIC_RELEASE, __HIP_MEMORY_SCOPE_AGENT);
    }
    // No trailing barrier needed: next-iter writes to x_lds/h_lds/hg_lds are
    // fenced from this iter's reads by B1/B2 of the next iteration.
  }
}

// ---------------------------------------------------------------------------
extern "C" void kernel_launch(void* const* d_in, const int* in_sizes, int n_in,
                              void* d_out, int out_size, void* d_ws, size_t ws_size,
                              hipStream_t stream) {
  const float* xs     = (const float*)d_in[0];
  const float* w_ih   = (const float*)d_in[1];
  const float* w_hh   = (const float*)d_in[2];
  const float* bias   = (const float*)d_in[3];
  const float* bias_n = (const float*)d_in[4];
  float* out   = (float*)d_out;
  u64*   hslot = (u64*)d_ws;  // [2][512] tagged slots = 8 KB

  hipMemsetAsync(d_ws, 0, 2 * HSZ * sizeof(u64), stream);  // tags=0 => h_0=0
  gru_fused<<<NBLK, 256, 0, stream>>>(xs, w_ih, w_hh, bias, bias_n, hslot, out);
}

// Round 6
// 139972.546 us; speedup vs baseline: 1.7345x; 1.7345x over previous
//
#include <hip/hip_runtime.h>
#include <stdint.h>

typedef unsigned long long u64;
typedef float f32x32 __attribute__((ext_vector_type(32)));
typedef float f32x16 __attribute__((ext_vector_type(16)));

#define T_TOTAL 65536
#define ISZ 256
#define HSZ 512
#define NWORK 32
#define SLICE 16   // HSZ / NWORK

// LDS skew (word index): +4 words per row -> max 2-way bank aliasing (free).
__device__ __forceinline__ int HSW(int i) { return i + ((i >> 5) << 2); }  // rows of 32
__device__ __forceinline__ int XSW(int i) { return i + ((i >> 4) << 2); }  // rows of 16

struct Ctl { int grank; int chosen; int fastctr; int done; int slowctr; int pad[11]; };

// Genuine TCC-executed dual poll: two atomic add-0 RMWs (sc0 = return old),
// both in flight, one waitcnt. Inline asm so InstCombine can NOT demote the
// idempotent RMW to an (L1-cacheable) atomic load — that demotion is what
// broke rounds 4/5: workgroup-scope relaxed loads spin on stale L1.
__device__ __forceinline__ void poll2_rmw(u64* p0, u64* p1, u64& q0, u64& q1) {
  u64 zero = 0;
  asm volatile(
      "global_atomic_add_x2 %0, %2, %4, off sc0\n\t"
      "global_atomic_add_x2 %1, %3, %4, off sc0\n\t"
      "s_waitcnt vmcnt(0)"
      : "=&v"(q0), "=&v"(q1)
      : "v"(p0), "v"(p1), "v"(zero)
      : "memory");
}
__device__ __forceinline__ void publish_rmw(u64* p, u64 v) {
  asm volatile("global_atomic_swap_x2 %0, %1, off" :: "v"(p), "v"(v) : "memory");
}

// ---------------------------------------------------------------------------
// Persistent fused GRU scan.
// Sync: tagged 64-bit slots {tag=version, f32 value}; parity-2 slot ring.
// FAST mode (32 workers verified on ONE XCD): poll/publish are inline-asm
//   atomic RMWs -> execute in that XCD's TCC (L2). Single TCC => coherent.
// SLOW fallback (election failed): Round-2-proven protocol — acquire loads /
//   release stores at AGENT scope (MALL-coherent across XCDs).
//
// Memory-safety with ONE barrier (B2) per step:
//  - h_lds double-buffered by parity: writes@s+1 hit (s+1)&1, reads@s hit
//    s&1. Reuse at s+2 gated by poll(s+2): tag s+2 implies every block passed
//    B2(s+1); each wave reaches B2(s+1) only after (program order) finishing
//    its ENTIRE iter-s body, including matvec reads of h_lds[s&1].
//  - x_lds double-buffered: writes@s+1 (to [s&1... i.e. nxt'—the buffer read
//    at s) occur after B2(s); all reads of that buffer at iter s occur before
//    B2(s) in every wave's program order.
//  - Slot-overwrite: C publishes tag s+2 into parity cur only after observing
//    all 512 tag-(s+1) publishes, each issued after its block's B2(s), i.e.
//    after ALL that block's poll RMWs for parity cur executed in the TCC.
// Spin fuse bounds worst-case runtime (fail with wrong data, never wedge).
// ---------------------------------------------------------------------------
__global__ __launch_bounds__(256, 1) void gru_fused(
    const float* __restrict__ xs, const float* __restrict__ w_ih,
    const float* __restrict__ w_hh, const float* __restrict__ bias,
    const float* __restrict__ bias_n, u64* __restrict__ hslot,
    Ctl* __restrict__ ctl, float* __restrict__ out) {
  const int tid = threadIdx.x;
  const int seg = tid & 15;   // K-segment: h[32*seg..+32), x[16*seg..+16)
  const int rg  = tid >> 4;   // unit within slice (0..15)

  __shared__ int s_role, s_fast;
  __shared__ __align__(16) float x_lds[2][320];
  __shared__ __align__(16) float h_lds[2][576];

  // ---- election: verify 32 blocks on one XCD, else agent-scope fallback
  if (tid == 0) {
    unsigned xcc = 0;
    asm volatile("s_getreg_b32 %0, hwreg(HW_REG_XCC_ID)" : "=s"(xcc));
    long long eb = 100000000;
    int rank = __hip_atomic_fetch_add(&ctl->grank, 1, __ATOMIC_RELAXED,
                                      __HIP_MEMORY_SCOPE_AGENT);
    if (rank == 0)
      __hip_atomic_store(&ctl->chosen, (int)xcc + 1, __ATOMIC_RELEASE,
                         __HIP_MEMORY_SCOPE_AGENT);
    int chosen;
    do { chosen = __hip_atomic_load(&ctl->chosen, __ATOMIC_ACQUIRE,
                                    __HIP_MEMORY_SCOPE_AGENT); }
    while (chosen == 0 && --eb > 0);
    int fr = -1;
    if ((int)xcc == chosen - 1)
      fr = __hip_atomic_fetch_add(&ctl->fastctr, 1, __ATOMIC_RELAXED,
                                  __HIP_MEMORY_SCOPE_AGENT);
    __hip_atomic_fetch_add(&ctl->done, 1, __ATOMIC_ACQ_REL,
                           __HIP_MEMORY_SCOPE_AGENT);
    int dn;
    do { dn = __hip_atomic_load(&ctl->done, __ATOMIC_ACQUIRE,
                                __HIP_MEMORY_SCOPE_AGENT); }
    while (dn < (int)gridDim.x && --eb > 0);
    int fc = __hip_atomic_load(&ctl->fastctr, __ATOMIC_ACQUIRE,
                               __HIP_MEMORY_SCOPE_AGENT);
    int fast = (fc >= NWORK && dn >= (int)gridDim.x) ? 1 : 0;
    int role = -1;
    if (fast) {
      if (fr >= 0 && fr < NWORK) role = fr;
    } else {
      int sr = __hip_atomic_fetch_add(&ctl->slowctr, 1, __ATOMIC_RELAXED,
                                      __HIP_MEMORY_SCOPE_AGENT);
      if (sr < NWORK) role = sr;
    }
    s_role = role; s_fast = fast;
  }
  __syncthreads();
  const int role = s_role;   // uniform per block
  const int fast = s_fast;
  if (role < 0) return;      // whole block exits together

  // ---- weights into true VGPRs (ext_vector, static indexing only) ----
  f32x32 wh0, wh1, wh2;
  f32x16 wi0, wi1, wi2;
  {
    const float* h0 = w_hh + (size_t)(0 * HSZ + role * SLICE + rg) * HSZ + seg * 32;
    const float* h1 = w_hh + (size_t)(1 * HSZ + role * SLICE + rg) * HSZ + seg * 32;
    const float* h2 = w_hh + (size_t)(2 * HSZ + role * SLICE + rg) * HSZ + seg * 32;
#pragma unroll
    for (int u = 0; u < 8; ++u) {
      float4 a = *(const float4*)(h0 + u * 4);
      float4 b = *(const float4*)(h1 + u * 4);
      float4 c = *(const float4*)(h2 + u * 4);
      wh0[u*4+0]=a.x; wh0[u*4+1]=a.y; wh0[u*4+2]=a.z; wh0[u*4+3]=a.w;
      wh1[u*4+0]=b.x; wh1[u*4+1]=b.y; wh1[u*4+2]=b.z; wh1[u*4+3]=b.w;
      wh2[u*4+0]=c.x; wh2[u*4+1]=c.y; wh2[u*4+2]=c.z; wh2[u*4+3]=c.w;
    }
    const float* i0 = w_ih + (size_t)(0 * HSZ + role * SLICE + rg) * ISZ + seg * 16;
    const float* i1 = w_ih + (size_t)(1 * HSZ + role * SLICE + rg) * ISZ + seg * 16;
    const float* i2 = w_ih + (size_t)(2 * HSZ + role * SLICE + rg) * ISZ + seg * 16;
#pragma unroll
    for (int u = 0; u < 4; ++u) {
      float4 a = *(const float4*)(i0 + u * 4);
      float4 b = *(const float4*)(i1 + u * 4);
      float4 c = *(const float4*)(i2 + u * 4);
      wi0[u*4+0]=a.x; wi0[u*4+1]=a.y; wi0[u*4+2]=a.z; wi0[u*4+3]=a.w;
      wi1[u*4+0]=b.x; wi1[u*4+1]=b.y; wi1[u*4+2]=b.z; wi1[u*4+3]=b.w;
      wi2[u*4+0]=c.x; wi2[u*4+1]=c.y; wi2[u*4+2]=c.z; wi2[u*4+3]=c.w;
    }
  }
  const float br  = bias[role * SLICE + rg];
  const float bz  = bias[HSZ + role * SLICE + rg];
  const float bnn = bias[2 * HSZ + role * SLICE + rg];
  const float bn2 = bias_n[role * SLICE + rg];

  // prologue: stage x[0]
  if (tid < 64) {
    float4 v = *(const float4*)(xs + tid * 4);
    *(float4*)&x_lds[0][XSW(tid * 4)] = v;
  }
  __syncthreads();

  long long budget = 50000000;  // spin fuse

  for (int s = 0; s < T_TOTAL; ++s) {
    const int cur = s & 1, nxt = cur ^ 1;

    // x[s+1] prefetch (off-chain; HBM latency hides under the h-wait).
    float4 xpf;
    if (tid < 64) {
      int srow = (s + 1 < T_TOTAL) ? (s + 1) : s;
      xpf = *(const float4*)(xs + (size_t)srow * ISZ + tid * 4);
    }

    // Input-side gate dots (independent of h). a3 = hidden-side n, separate.
    float a0 = 0.f, a1 = 0.f, a2 = 0.f, a3 = 0.f;
#pragma unroll
    for (int u = 0; u < 4; ++u) {
      float4 xv = *(const float4*)&x_lds[cur][XSW(seg * 16 + u * 4)];
      a0 += wi0[u*4+0]*xv.x + wi0[u*4+1]*xv.y + wi0[u*4+2]*xv.z + wi0[u*4+3]*xv.w;
      a1 += wi1[u*4+0]*xv.x + wi1[u*4+1]*xv.y + wi1[u*4+2]*xv.z + wi1[u*4+3]*xv.w;
      a2 += wi2[u*4+0]*xv.x + wi2[u*4+1]*xv.y + wi2[u*4+2]*xv.z + wi2[u*4+3]*xv.w;
    }
    if (tid < 64) *(float4*)&x_lds[nxt][XSW(tid * 4)] = xpf;  // after B2(s-1): safe

    // Poll h version s.
    u64* sb = hslot + (size_t)cur * HSZ;
    u64 q0, q1;
    if (fast) {
      for (;;) {
        poll2_rmw(&sb[tid], &sb[tid + 256], q0, q1);
        if (((unsigned)(q0 >> 32) == (unsigned)s) &
            ((unsigned)(q1 >> 32) == (unsigned)s)) break;
        if (--budget <= 0) break;
      }
    } else {
      do {
        q0 = __hip_atomic_load(&sb[tid], __ATOMIC_ACQUIRE, __HIP_MEMORY_SCOPE_AGENT);
      } while ((unsigned)(q0 >> 32) != (unsigned)s && --budget > 0);
      do {
        q1 = __hip_atomic_load(&sb[tid + 256], __ATOMIC_ACQUIRE, __HIP_MEMORY_SCOPE_AGENT);
      } while ((unsigned)(q1 >> 32) != (unsigned)s && --budget > 0);
    }
    h_lds[cur][HSW(tid)]       = __uint_as_float((unsigned)q0);
    h_lds[cur][HSW(tid + 256)] = __uint_as_float((unsigned)q1);
    __syncthreads();  // B2: h ready (only barrier per step)

    // Hidden-side dots (critical chain): 3 rows x 32-wide segment.
#pragma unroll
    for (int u = 0; u < 8; ++u) {
      float4 hv = *(const float4*)&h_lds[cur][HSW(seg * 32 + u * 4)];
      a0 += wh0[u*4+0]*hv.x + wh0[u*4+1]*hv.y + wh0[u*4+2]*hv.z + wh0[u*4+3]*hv.w;
      a1 += wh1[u*4+0]*hv.x + wh1[u*4+1]*hv.y + wh1[u*4+2]*hv.z + wh1[u*4+3]*hv.w;
      a3 += wh2[u*4+0]*hv.x + wh2[u*4+1]*hv.y + wh2[u*4+2]*hv.z + wh2[u*4+3]*hv.w;
    }

    // Butterfly reduce over the 16 seg-lanes (bits 0..3 of lane id).
#pragma unroll
    for (int p = 0; p < 4; ++p) {
      int m = 1 << p;
      a0 += __shfl_xor(a0, m, 64);
      a1 += __shfl_xor(a1, m, 64);
      a2 += __shfl_xor(a2, m, 64);
      a3 += __shfl_xor(a3, m, 64);
    }

    if (seg == 0) {  // lane rg*16 owns unit role*16+rg: epilogue+publish+out
      float r  = 1.f / (1.f + __expf(-(br + a0)));
      float z  = 1.f / (1.f + __expf(-(bz + a1)));
      float tv = bnn + a2 + r * (a3 + bn2);
      float nn = 1.f - 2.f / (__expf(2.f * tv) + 1.f);  // tanh, exact limits
      const int hid = role * SLICE + rg;
      float hold = h_lds[cur][HSW(hid)];
      float hnew = nn + z * (hold - nn);
      u64 pw = ((u64)(unsigned)(s + 1) << 32) | (u64)__float_as_uint(hnew);
      u64* pp = &hslot[(size_t)nxt * HSZ + hid];
      if (fast)
        publish_rmw(pp, pw);
      else
        __hip_atomic_store(pp, pw, __ATOMIC_RELEASE, __HIP_MEMORY_SCOPE_AGENT);
      out[(size_t)HSZ + (size_t)s * HSZ + hid] = hnew;
      if (s == T_TOTAL - 1) out[hid] = hnew;
    }
  }
}

// ---------------------------------------------------------------------------
extern "C" void kernel_launch(void* const* d_in, const int* in_sizes, int n_in,
                              void* d_out, int out_size, void* d_ws, size_t ws_size,
                              hipStream_t stream) {
  const float* xs     = (const float*)d_in[0];
  const float* w_ih   = (const float*)d_in[1];
  const float* w_hh   = (const float*)d_in[2];
  const float* bias   = (const float*)d_in[3];
  const float* bias_n = (const float*)d_in[4];
  float* out   = (float*)d_out;
  u64*   hslot = (u64*)d_ws;                   // [2][512] tagged slots = 8 KB
  Ctl*   ctl   = (Ctl*)((char*)d_ws + 8192);   // election control

  hipMemsetAsync(d_ws, 0, 12288, stream);      // tags=0 => h_0 = 0; ctl = 0
  gru_fused<<<256, 256, 0, stream>>>(xs, w_ih, w_hh, bias, bias_n, hslot, ctl, out);
}

// Round 8
// 131939.062 us; speedup vs baseline: 1.8401x; 1.0609x over previous
//
#include <hip/hip_runtime.h>
#include <stdint.h>

typedef unsigned long long u64;
typedef float f32x32 __attribute__((ext_vector_type(32)));
typedef float f32x16 __attribute__((ext_vector_type(16)));

#define T_TOTAL 65536
#define ISZ 256
#define HSZ 512
#define NWORK 16
#define SLICE 32   // HSZ / NWORK
#define NTHR 512

// LDS skew (word index): +4 words per row -> max 2-way bank aliasing (free).
__device__ __forceinline__ int HSW(int i) { return i + ((i >> 5) << 2); }  // rows of 32
__device__ __forceinline__ int XSW(int i) { return i + ((i >> 4) << 2); }  // rows of 16

struct Ctl { int grank; int chosen; int fastctr; int done; int slowctr; int pad[11]; };

// Poll = genuine TCC-executed atomic RMW (add 0, sc0 returns old value).
// Inline asm so InstCombine cannot demote the idempotent RMW to an atomic
// LOAD: every load-path poll variant (R3 sc0 loads, R4/R5 demoted RMWs,
// R7 buffer_inv+loads) read stale data on gfx950; only RMWs are proven.
__device__ __forceinline__ u64 poll1_rmw(u64* p, unsigned sv, long long& budget) {
  u64 q, zero = 0;
  for (;;) {
    asm volatile("global_atomic_add_x2 %0, %1, %2, off sc0\n\t"
                 "s_waitcnt vmcnt(0)"
                 : "=&v"(q) : "v"(p), "v"(zero) : "memory");
    if ((unsigned)(q >> 32) == sv) break;
    if (--budget <= 0) break;
  }
  return q;
}
__device__ __forceinline__ void publish_rmw(u64* p, u64 v) {
  asm volatile("global_atomic_swap_x2 %0, %1, off" :: "v"(p), "v"(v) : "memory");
}

// ---------------------------------------------------------------------------
// Persistent fused GRU scan, 16 blocks x 512 threads (was 32x256): the scan
// is TCC-atomic-THROUGHPUT-bound (R6: 22K RMW/step ~ 2.1us/step), and poll
// RMWs/step = NBLK*512, so halving NBLK halves the bottleneck. Slots padded
// to 16 B to double the cache-line spread (halves per-line serialization).
//
// Sync: tagged 64-bit slots {tag=version, f32 value}; parity-2 slot ring.
// FAST mode (16 workers verified on ONE XCD): poll/publish RMWs execute in
// that XCD's TCC. SLOW fallback: agent-scope acquire/release (R2-proven).
//
// Memory-safety with ONE barrier (B2) per step:
//  - h_lds double-buffered by parity; intra-block: wave Wa's iter-(s+2)
//    writes happen after Wa passed B2(s+1), which implies every wave finished
//    its iter-s reads. Inter-block: tag s on all units implies the owning
//    blocks passed B2(s-1), i.e. finished all their parity polls.
//  - x_lds double-buffered: writes@s+1 after B2(s); reads@s before B2(s).
// Spin fuse bounds worst-case runtime (fail with wrong data, never wedge).
// ---------------------------------------------------------------------------
__global__ __launch_bounds__(NTHR, 1) void gru_fused(
    const float* __restrict__ xs, const float* __restrict__ w_ih,
    const float* __restrict__ w_hh, const float* __restrict__ bias,
    const float* __restrict__ bias_n, u64* __restrict__ hslot,
    Ctl* __restrict__ ctl, float* __restrict__ out) {
  const int tid = threadIdx.x;
  const int seg = tid & 15;   // K-segment: h[32*seg..+32), x[16*seg..+16)
  const int rg  = tid >> 4;   // unit within slice (0..31)

  __shared__ int s_role, s_fast;
  __shared__ __align__(16) float x_lds[2][320];
  __shared__ __align__(16) float h_lds[2][576];

  // ---- election: verify 16 blocks on one XCD, else agent-scope fallback
  if (tid == 0) {
    unsigned xcc = 0;
    asm volatile("s_getreg_b32 %0, hwreg(HW_REG_XCC_ID)" : "=s"(xcc));
    long long eb = 100000000;
    int rank = __hip_atomic_fetch_add(&ctl->grank, 1, __ATOMIC_RELAXED,
                                      __HIP_MEMORY_SCOPE_AGENT);
    if (rank == 0)
      __hip_atomic_store(&ctl->chosen, (int)xcc + 1, __ATOMIC_RELEASE,
                         __HIP_MEMORY_SCOPE_AGENT);
    int chosen;
    do { chosen = __hip_atomic_load(&ctl->chosen, __ATOMIC_ACQUIRE,
                                    __HIP_MEMORY_SCOPE_AGENT); }
    while (chosen == 0 && --eb > 0);
    int fr = -1;
    if ((int)xcc == chosen - 1)
      fr = __hip_atomic_fetch_add(&ctl->fastctr, 1, __ATOMIC_RELAXED,
                                  __HIP_MEMORY_SCOPE_AGENT);
    __hip_atomic_fetch_add(&ctl->done, 1, __ATOMIC_ACQ_REL,
                           __HIP_MEMORY_SCOPE_AGENT);
    int dn;
    do { dn = __hip_atomic_load(&ctl->done, __ATOMIC_ACQUIRE,
                                __HIP_MEMORY_SCOPE_AGENT); }
    while (dn < (int)gridDim.x && --eb > 0);
    int fc = __hip_atomic_load(&ctl->fastctr, __ATOMIC_ACQUIRE,
                               __HIP_MEMORY_SCOPE_AGENT);
    int fast = (fc >= NWORK && dn >= (int)gridDim.x) ? 1 : 0;
    int role = -1;
    if (fast) {
      if (fr >= 0 && fr < NWORK) role = fr;
    } else {
      int sr = __hip_atomic_fetch_add(&ctl->slowctr, 1, __ATOMIC_RELAXED,
                                      __HIP_MEMORY_SCOPE_AGENT);
      if (sr < NWORK) role = sr;
    }
    s_role = role; s_fast = fast;
  }
  __syncthreads();
  const int role = s_role;   // uniform per block
  const int fast = s_fast;
  if (role < 0) return;      // whole block exits together

  // ---- weights into true VGPRs (ext_vector, static indexing only) ----
  f32x32 wh0, wh1, wh2;
  f32x16 wi0, wi1, wi2;
  {
    const float* h0 = w_hh + (size_t)(0 * HSZ + role * SLICE + rg) * HSZ + seg * 32;
    const float* h1 = w_hh + (size_t)(1 * HSZ + role * SLICE + rg) * HSZ + seg * 32;
    const float* h2 = w_hh + (size_t)(2 * HSZ + role * SLICE + rg) * HSZ + seg * 32;
#pragma unroll
    for (int u = 0; u < 8; ++u) {
      float4 a = *(const float4*)(h0 + u * 4);
      float4 b = *(const float4*)(h1 + u * 4);
      float4 c = *(const float4*)(h2 + u * 4);
      wh0[u*4+0]=a.x; wh0[u*4+1]=a.y; wh0[u*4+2]=a.z; wh0[u*4+3]=a.w;
      wh1[u*4+0]=b.x; wh1[u*4+1]=b.y; wh1[u*4+2]=b.z; wh1[u*4+3]=b.w;
      wh2[u*4+0]=c.x; wh2[u*4+1]=c.y; wh2[u*4+2]=c.z; wh2[u*4+3]=c.w;
    }
    const float* i0 = w_ih + (size_t)(0 * HSZ + role * SLICE + rg) * ISZ + seg * 16;
    const float* i1 = w_ih + (size_t)(1 * HSZ + role * SLICE + rg) * ISZ + seg * 16;
    const float* i2 = w_ih + (size_t)(2 * HSZ + role * SLICE + rg) * ISZ + seg * 16;
#pragma unroll
    for (int u = 0; u < 4; ++u) {
      float4 a = *(const float4*)(i0 + u * 4);
      float4 b = *(const float4*)(i1 + u * 4);
      float4 c = *(const float4*)(i2 + u * 4);
      wi0[u*4+0]=a.x; wi0[u*4+1]=a.y; wi0[u*4+2]=a.z; wi0[u*4+3]=a.w;
      wi1[u*4+0]=b.x; wi1[u*4+1]=b.y; wi1[u*4+2]=b.z; wi1[u*4+3]=b.w;
      wi2[u*4+0]=c.x; wi2[u*4+1]=c.y; wi2[u*4+2]=c.z; wi2[u*4+3]=c.w;
    }
  }
  const int myunit = role * SLICE + rg;   // unit this thread's rows belong to
  const float br  = bias[myunit];
  const float bz  = bias[HSZ + myunit];
  const float bnn = bias[2 * HSZ + myunit];
  const float bn2 = bias_n[myunit];

  // prologue: stage x[0]
  if (tid < 64) {
    float4 v = *(const float4*)(xs + tid * 4);
    *(float4*)&x_lds[0][XSW(tid * 4)] = v;
  }
  __syncthreads();

  long long budget = 20000000;  // spin fuse (fail visibly, never wedge)

  for (int s = 0; s < T_TOTAL; ++s) {
    const int cur = s & 1, nxt = cur ^ 1;

    // x[s+1] prefetch (off-chain; HBM latency hides under the h-wait).
    float4 xpf;
    if (tid < 64) {
      int srow = (s + 1 < T_TOTAL) ? (s + 1) : s;
      xpf = *(const float4*)(xs + (size_t)srow * ISZ + tid * 4);
    }

    // Input-side gate dots (independent of h). a3 = hidden-side n, separate.
    float a0 = 0.f, a1 = 0.f, a2 = 0.f, a3 = 0.f;
#pragma unroll
    for (int u = 0; u < 4; ++u) {
      float4 xv = *(const float4*)&x_lds[cur][XSW(seg * 16 + u * 4)];
      a0 += wi0[u*4+0]*xv.x + wi0[u*4+1]*xv.y + wi0[u*4+2]*xv.z + wi0[u*4+3]*xv.w;
      a1 += wi1[u*4+0]*xv.x + wi1[u*4+1]*xv.y + wi1[u*4+2]*xv.z + wi1[u*4+3]*xv.w;
      a2 += wi2[u*4+0]*xv.x + wi2[u*4+1]*xv.y + wi2[u*4+2]*xv.z + wi2[u*4+3]*xv.w;
    }
    if (tid < 64) *(float4*)&x_lds[nxt][XSW(tid * 4)] = xpf;  // after B2(s-1): safe

    // Poll h version s: each of the 512 threads polls exactly one slot
    // (slots padded to 16 B -> 8 per 128 B line -> halved line contention).
    u64* sb = hslot + (size_t)cur * (HSZ * 2);
    u64 q0;
    if (fast) {
      q0 = poll1_rmw(&sb[2 * tid], (unsigned)s, budget);
    } else {
      do {
        q0 = __hip_atomic_load(&sb[2 * tid], __ATOMIC_ACQUIRE, __HIP_MEMORY_SCOPE_AGENT);
      } while ((unsigned)(q0 >> 32) != (unsigned)s && --budget > 0);
    }
    h_lds[cur][HSW(tid)] = __uint_as_float((unsigned)q0);
    __syncthreads();  // B2: h ready (only barrier per step)

    // Hidden-side dots (critical chain): 3 rows x 32-wide segment.
#pragma unroll
    for (int u = 0; u < 8; ++u) {
      float4 hv = *(const float4*)&h_lds[cur][HSW(seg * 32 + u * 4)];
      a0 += wh0[u*4+0]*hv.x + wh0[u*4+1]*hv.y + wh0[u*4+2]*hv.z + wh0[u*4+3]*hv.w;
      a1 += wh1[u*4+0]*hv.x + wh1[u*4+1]*hv.y + wh1[u*4+2]*hv.z + wh1[u*4+3]*hv.w;
      a3 += wh2[u*4+0]*hv.x + wh2[u*4+1]*hv.y + wh2[u*4+2]*hv.z + wh2[u*4+3]*hv.w;
    }

    // Butterfly reduce over the 16 seg-lanes (bits 0..3 of lane id).
#pragma unroll
    for (int p = 0; p < 4; ++p) {
      int m = 1 << p;
      a0 += __shfl_xor(a0, m, 64);
      a1 += __shfl_xor(a1, m, 64);
      a2 += __shfl_xor(a2, m, 64);
      a3 += __shfl_xor(a3, m, 64);
    }

    if (seg == 0) {  // one lane per hidden unit: epilogue + publish + out
      float r  = 1.f / (1.f + __expf(-(br + a0)));
      float z  = 1.f / (1.f + __expf(-(bz + a1)));
      float tv = bnn + a2 + r * (a3 + bn2);
      float nn = 1.f - 2.f / (__expf(2.f * tv) + 1.f);  // tanh, exact limits
      float hold = h_lds[cur][HSW(myunit)];
      float hnew = nn + z * (hold - nn);
      u64 pw = ((u64)(unsigned)(s + 1) << 32) | (u64)__float_as_uint(hnew);
      u64* pp = &hslot[(size_t)nxt * (HSZ * 2) + 2 * myunit];
      if (fast)
        publish_rmw(pp, pw);
      else
        __hip_atomic_store(pp, pw, __ATOMIC_RELEASE, __HIP_MEMORY_SCOPE_AGENT);
      out[(size_t)HSZ + (size_t)s * HSZ + myunit] = hnew;
      if (s == T_TOTAL - 1) out[myunit] = hnew;
    }
  }
}

// ---------------------------------------------------------------------------
extern "C" void kernel_launch(void* const* d_in, const int* in_sizes, int n_in,
                              void* d_out, int out_size, void* d_ws, size_t ws_size,
                              hipStream_t stream) {
  const float* xs     = (const float*)d_in[0];
  const float* w_ih   = (const float*)d_in[1];
  const float* w_hh   = (const float*)d_in[2];
  const float* bias   = (const float*)d_in[3];
  const float* bias_n = (const float*)d_in[4];
  float* out   = (float*)d_out;
  u64*   hslot = (u64*)d_ws;                    // [2][512] padded slots = 16 KB
  Ctl*   ctl   = (Ctl*)((char*)d_ws + 16384);   // election control

  hipMemsetAsync(d_ws, 0, 16384 + 256, stream); // tags=0 => h_0 = 0; ctl = 0
  gru_fused<<<256, NTHR, 0, stream>>>(xs, w_ih, w_hh, bias, bias_n, hslot, ctl, out);
}